// Round 14
// baseline (462.970 us; speedup 1.0000x reference)
//
#include <hip/hip_runtime.h>

using f32x4 = __attribute__((ext_vector_type(4))) float;
using s16x8 = __attribute__((ext_vector_type(8))) short;
using u16x4 = __attribute__((ext_vector_type(4))) unsigned short;
using u32 = unsigned int;

static __device__ __forceinline__ unsigned short f2bf(float f) {
  u32 u = __builtin_bit_cast(u32, f);
  u = (u + 0x7fffu + ((u >> 16) & 1u)) >> 16;
  return (unsigned short)u;
}

static __device__ __forceinline__ void gload_lds16(const void* g, void* l) {
  __builtin_amdgcn_global_load_lds((const __attribute__((address_space(1))) void*)g,
                                   (__attribute__((address_space(3))) void*)l, 16, 0, 0);
}

// ---------------- fused fp32 -> bf16 conversion (all 6 tensors, one launch) ----------------
__global__ void k_cvt_all(const float* __restrict__ x, const float* __restrict__ Wqd,
                          const float* __restrict__ Wkd, const float* __restrict__ Wvd,
                          const float* __restrict__ Wvu, const float* __restrict__ Wo,
                          unsigned short* __restrict__ xb, unsigned short* __restrict__ Wdb,
                          unsigned short* __restrict__ Wvub, unsigned short* __restrict__ Wob) {
  int i = blockIdx.x * blockDim.x + threadIdx.x;  // float4 index, total 1572864
  const float* s;
  unsigned short* d;
  int off;
  if (i < 1048576) { s = x; d = xb; off = i; }
  else if (i < 1114112) { s = Wqd; d = Wdb; off = i - 1048576; }
  else if (i < 1179648) { s = Wkd; d = Wdb + 262144; off = i - 1114112; }
  else if (i < 1245184) { s = Wvd; d = Wdb + 524288; off = i - 1179648; }
  else if (i < 1310720) { s = Wvu; d = Wvub; off = i - 1245184; }
  else { s = Wo; d = Wob; off = i - 1310720; }
  float4 v = reinterpret_cast<const float4*>(s)[off];
  u16x4 o;
  o[0] = f2bf(v.x); o[1] = f2bf(v.y); o[2] = f2bf(v.z); o[3] = f2bf(v.w);
  reinterpret_cast<u16x4*>(d)[off] = o;
}

// ---------------- MabsT[h][k][q] = 0.125 * sum_d Wq_up[h*64+d][q] * Wk_up[h*64+d][k] ----------------
__global__ void k_mabs(const float* __restrict__ Wqu, const float* __restrict__ Wku,
                       unsigned short* __restrict__ MabsT) {
  __shared__ float sq[64][65];
  __shared__ float sk[64][65];
  int h = blockIdx.z, q0 = blockIdx.x * 64, k0 = blockIdx.y * 64;
  int t = threadIdx.x;
  for (int r = 0; r < 16; ++r) {
    int d = r * 4 + (t >> 6);
    int c = t & 63;
    sq[d][c] = Wqu[(size_t)(h * 64 + d) * 256 + q0 + c];
    sk[d][c] = Wku[(size_t)(h * 64 + d) * 256 + k0 + c];
  }
  __syncthreads();
  int kk = t >> 2, qs = t & 3;
  float acc[16];
#pragma unroll
  for (int j = 0; j < 16; ++j) acc[j] = 0.f;
  for (int d = 0; d < 64; ++d) {
    float kv = sk[d][kk];
#pragma unroll
    for (int j = 0; j < 16; ++j) acc[j] += kv * sq[d][qs + 4 * j];
  }
#pragma unroll
  for (int j = 0; j < 16; ++j)
    MabsT[((size_t)(h * 256 + k0 + kk)) * 256 + q0 + qs + 4 * j] = f2bf(acc[j] * 0.125f);
}

// ---------------- NT-GEMM, gload_lds DOUBLE-buffered (prefetch overlaps MFMA) ----------------
// modes: 0 = bf16 C row-major; 1 = fp32 C row-major + bias; 2 = bf16 Qabs scatter
__global__ __launch_bounds__(256) void k_gemm(
    const unsigned short* __restrict__ A, int lda,
    const unsigned short* __restrict__ B0, int ldb, long bstride,
    void* __restrict__ C, const float* __restrict__ bias,
    int M, int N, int K, int ldc, int mode) {
  __shared__ unsigned short As[2][128 * 32];
  __shared__ unsigned short Bs[2][128 * 32];
  int bz = blockIdx.z;
  const unsigned short* B = B0 + (size_t)bz * bstride;
  int row0 = blockIdx.x * 128, col0 = blockIdx.y * 128;
  int t = threadIdx.x;
  int lane = t & 63, w = t >> 6;
  int wr = w >> 1, wc = w & 1;
  int lc = lane & 15, kr = (lane >> 4) * 8;

#define STAGE(bufi, k0g)                                                                   \
  {                                                                                        \
    _Pragma("unroll") for (int c = 0; c < 2; ++c) {                                        \
      int f = (c * 256 + t) * 16;                                                          \
      int r = f >> 6, kb = (f & 63) >> 1;                                                  \
      gload_lds16(A + (size_t)(row0 + r) * lda + (k0g) + kb,                               \
                  (char*)&As[bufi][0] + c * 4096 + w * 1024);                              \
    }                                                                                      \
    _Pragma("unroll") for (int c = 0; c < 2; ++c) {                                        \
      int f = (c * 256 + t) * 16;                                                          \
      int r = f >> 6, kb = (f & 63) >> 1;                                                  \
      gload_lds16(B + (size_t)(col0 + r) * ldb + (k0g) + kb,                               \
                  (char*)&Bs[bufi][0] + c * 4096 + w * 1024);                              \
    }                                                                                      \
  }

  f32x4 acc[4][4];
#pragma unroll
  for (int m = 0; m < 4; ++m)
#pragma unroll
    for (int n = 0; n < 4; ++n) acc[m][n] = (f32x4){0.f, 0.f, 0.f, 0.f};

  STAGE(0, 0)
  asm volatile("s_waitcnt vmcnt(0)" ::: "memory");
  __syncthreads();

  int cur = 0;
  for (int k0 = 0; k0 < K; k0 += 32) {
    const bool pfn = (k0 + 32 < K);
    if (pfn) { STAGE(cur ^ 1, k0 + 32) }

    s16x8 af[4], bf[4];
#pragma unroll
    for (int m = 0; m < 4; ++m)
      af[m] = *(const s16x8*)&As[cur][(wr * 64 + m * 16 + lc) * 32 + kr];
#pragma unroll
    for (int n = 0; n < 4; ++n)
      bf[n] = *(const s16x8*)&Bs[cur][(wc * 64 + n * 16 + lc) * 32 + kr];
#pragma unroll
    for (int m = 0; m < 4; ++m)
#pragma unroll
      for (int n = 0; n < 4; ++n)
        acc[m][n] = __builtin_amdgcn_mfma_f32_16x16x32_bf16(af[m], bf[n], acc[m][n], 0, 0, 0);

    asm volatile("s_waitcnt vmcnt(0)" ::: "memory");
    __syncthreads();
    cur ^= 1;
  }

  int rbase = row0 + wr * 64, cbase = col0 + wc * 64;
  int lr4 = (lane >> 4) * 4;
#pragma unroll
  for (int m = 0; m < 4; ++m)
#pragma unroll
    for (int n = 0; n < 4; ++n)
#pragma unroll
      for (int r = 0; r < 4; ++r) {
        int grow = rbase + m * 16 + lr4 + r;
        int gcol = cbase + n * 16 + lc;
        float v = acc[m][n][r];
        if (mode == 0) {
          ((unsigned short*)C)[(size_t)grow * ldc + gcol] = f2bf(v);
        } else if (mode == 1) {
          ((float*)C)[(size_t)grow * ldc + gcol] = v + bias[gcol];
        } else {
          int b_ = grow >> 11, t_ = grow & 2047;
          ((unsigned short*)C)[(((size_t)(b_ * 16 + bz)) * 2048 + t_) * 256 + gcol] = f2bf(v);
        }
      }
#undef STAGE
}

// ---------------- flash attention: R13 math, V read direct from global (LDS 38.9KB -> 4 blocks/CU) ----------------
// Qabs [B*H][2048][256] bf16, K_lat inside Lat [B][2048][768] at col 256,
// VupT [1024 d][4096 s_glob] bf16 (d-major), ctx out [B][2048][1024] bf16
// Grid 32x32: one 64-row q-tile per block, heavy-first (bx=0 -> tile 31).
// K LDS [32][264] double-buffered; P per-wave [16][40]; V: per-step global reg prefetch.
__global__ __launch_bounds__(256, 2) void k_attn(
    const unsigned short* __restrict__ Qabs, const unsigned short* __restrict__ Lat,
    const unsigned short* __restrict__ VupT, unsigned short* __restrict__ ctx) {
  __shared__ unsigned short Ks[2][32 * 264];
  __shared__ unsigned short Pl[4][16 * 40];

  const int bx = blockIdx.x;
  const int bh = blockIdx.y;
  const int b = bh >> 4, h = bh & 15;
  const int t = threadIdx.x, lane = t & 63, w = t >> 6;
  const int lrow = lane & 15, hi = lane >> 4;
  const int kr = hi * 8;

  const unsigned short* Q = Qabs + (size_t)bh * 2048 * 256;
  const unsigned short* Kp = Lat + (size_t)b * 2048 * 768 + 256;
  const unsigned short* Vp = VupT + (size_t)(h * 64) * 4096 + b * 2048;
  unsigned short* Op = ctx + (size_t)b * 2048 * 1024 + h * 64;

  // K staging geometry: tile 32x256 shorts = 4x uint4/thread
  uint4 kstg[4];
  const int krr0 = t >> 5;  // K row within 8-row band; band c -> row c*8+krr0
  const int kcc = t & 31;   // 8-short chunk within K row

#define K_ISSUE(s0g)                                                           \
  {                                                                            \
    _Pragma("unroll") for (int c = 0; c < 4; ++c) kstg[c] =                    \
        *(const uint4*)(Kp + (size_t)((s0g) + c * 8 + krr0) * 768 + kcc * 8);  \
  }
#define K_WRITE(bufi)                                                          \
  {                                                                            \
    _Pragma("unroll") for (int c = 0; c < 4; ++c)                              \
        *(uint4*)&Ks[bufi][(c * 8 + krr0) * 264 + kcc * 8] = kstg[c];          \
  }

  // heavy-first: bx=0 takes the longest q-tile (LPT scheduling)
  const int tb = (31 - bx) * 64;
  const int qb = tb + w * 16;

  // Q fragments in registers
  s16x8 qf[8];
#pragma unroll
  for (int kk = 0; kk < 8; ++kk)
    qf[kk] = *(const s16x8*)&Q[(size_t)(qb + lrow) * 256 + kk * 32 + kr];

  f32x4 o[4];
#pragma unroll
  for (int dt = 0; dt < 4; ++dt) o[dt] = (f32x4){0.f, 0.f, 0.f, 0.f};
  float mrow[4], lsum[4];
  int myrow[4];
#pragma unroll
  for (int r = 0; r < 4; ++r) {
    mrow[r] = -1e30f;
    lsum[r] = 0.f;
    myrow[r] = qb + hi * 4 + r;
  }

  K_ISSUE(0)
  K_WRITE(0)
  __syncthreads();

  const int nsteps = tb / 32 + 2;
  for (int st = 0; st < nsteps; ++st) {
    const int buf = st & 1;
    const int s0 = st * 32;
    const bool pfn = (st + 1 < nsteps);
    if (pfn) { K_ISSUE(s0 + 32) }  // next K tile; written after PV (T14)

    // early V loads for THIS step (global, L2-resident slice); consumed in PV —
    // ~2000cy of QK+softmax hides the latency.
    uint4 vfr[4];
#pragma unroll
    for (int dt = 0; dt < 4; ++dt)
      vfr[dt] = *(const uint4*)(Vp + (size_t)(dt * 16 + lrow) * 4096 + s0 + kr);

    // ---- QK^T: batch-hoist all 16 K-fragment reads, then 16 MFMAs ----
    s16x8 kfa[2][8];
#pragma unroll
    for (int hf = 0; hf < 2; ++hf)
#pragma unroll
      for (int kk = 0; kk < 8; ++kk)
        kfa[hf][kk] = *(const s16x8*)&Ks[buf][(hf * 16 + lrow) * 264 + kk * 32 + kr];

    f32x4 sf[2];
    sf[0] = (f32x4){0.f, 0.f, 0.f, 0.f};
    sf[1] = (f32x4){0.f, 0.f, 0.f, 0.f};
    __builtin_amdgcn_s_setprio(1);
#pragma unroll
    for (int kk = 0; kk < 8; ++kk) {
      sf[0] = __builtin_amdgcn_mfma_f32_16x16x32_bf16(qf[kk], kfa[0][kk], sf[0], 0, 0, 0);
      sf[1] = __builtin_amdgcn_mfma_f32_16x16x32_bf16(qf[kk], kfa[1][kk], sf[1], 0, 0, 0);
    }
    __builtin_amdgcn_s_setprio(0);

    // ---- causal mask + online softmax (defer-max THR=8, per-lane lsum) ----
#pragma unroll
    for (int r = 0; r < 4; ++r) {
      int q = myrow[r];
      if (s0 + lrow > q) sf[0][r] = -1e30f;
      if (s0 + 16 + lrow > q) sf[1][r] = -1e30f;
      float mloc = fmaxf(sf[0][r], sf[1][r]);
      if (!__all(mloc <= mrow[r] + 8.f)) {
        float mx = mloc;
#pragma unroll
        for (int off = 1; off < 16; off <<= 1) mx = fmaxf(mx, __shfl_xor(mx, off));
        float mnew = fmaxf(mrow[r], mx);
        float scale = __expf(mrow[r] - mnew);
        mrow[r] = mnew;
        lsum[r] *= scale;
#pragma unroll
        for (int dt = 0; dt < 4; ++dt) o[dt][r] *= scale;
      }
      float p0 = __expf(sf[0][r] - mrow[r]);
      float p1 = __expf(sf[1][r] - mrow[r]);
      sf[0][r] = p0;
      sf[1][r] = p1;
      lsum[r] += p0 + p1;  // this lane's 2 cols only; reduced in epilogue
    }
    // P -> LDS (per-wave buffer)
#pragma unroll
    for (int r = 0; r < 4; ++r) {
      Pl[w][(hi * 4 + r) * 40 + lrow] = f2bf(sf[0][r]);
      Pl[w][(hi * 4 + r) * 40 + 16 + lrow] = f2bf(sf[1][r]);
    }
    // per-wave fence: P writes drained & ordered before pf read (Pl is per-wave)
    asm volatile("s_waitcnt lgkmcnt(0)" ::: "memory");
    __builtin_amdgcn_sched_barrier(0);

    // ---- PV: pf from LDS, vf from the early global prefetch ----
    s16x8 pf = *(const s16x8*)&Pl[w][lrow * 40 + kr];
    __builtin_amdgcn_s_setprio(1);
#pragma unroll
    for (int dt = 0; dt < 4; ++dt)
      o[dt] = __builtin_amdgcn_mfma_f32_16x16x32_bf16(
          pf, __builtin_bit_cast(s16x8, vfr[dt]), o[dt], 0, 0, 0);
    __builtin_amdgcn_s_setprio(0);

    if (pfn) { K_WRITE(buf ^ 1) }  // compiler inserts vmcnt wait on kstg
    __syncthreads();               // single barrier/step
  }

  // ---- epilogue: reduce lsum across the 16-lane row group once, write ctx ----
#pragma unroll
  for (int r = 0; r < 4; ++r) {
    float ls = lsum[r];
#pragma unroll
    for (int off = 1; off < 16; off <<= 1) ls += __shfl_xor(ls, off);
    lsum[r] = ls;
  }
#pragma unroll
  for (int dt = 0; dt < 4; ++dt)
#pragma unroll
    for (int r = 0; r < 4; ++r) {
      float v = o[dt][r] / lsum[r];
      Op[(size_t)myrow[r] * 1024 + dt * 16 + lrow] = f2bf(v);
    }
#undef K_ISSUE
#undef K_WRITE
}

extern "C" void kernel_launch(void* const* d_in, const int* in_sizes, int n_in,
                              void* d_out, int out_size, void* d_ws, size_t ws_size,
                              hipStream_t stream) {
  const float* x = (const float*)d_in[0];
  const float* Wqd = (const float*)d_in[2];
  const float* Wkd = (const float*)d_in[3];
  const float* Wvd = (const float*)d_in[4];
  const float* Wqu = (const float*)d_in[5];
  const float* Wku = (const float*)d_in[6];
  const float* Wvu = (const float*)d_in[7];
  const float* Wo = (const float*)d_in[8];
  const float* bo = (const float*)d_in[9];
  float* out = (float*)d_out;

  char* ws = (char*)d_ws;
  unsigned short* xb = (unsigned short*)(ws);                // 4096x1024 bf16
  unsigned short* Wdb = (unsigned short*)(ws + 8388608);     // 768x1024
  unsigned short* Wvub = (unsigned short*)(ws + 9961472);    // 1024x256
  unsigned short* Wob = (unsigned short*)(ws + 10485760);    // 1024x1024
  unsigned short* MabsT = (unsigned short*)(ws + 12582912);  // 16x256x256
  unsigned short* Lat = (unsigned short*)(ws + 14680064);    // 4096x768 (Q|K|V latents)
  unsigned short* Qabs = (unsigned short*)(ws + 20971520);   // 32x2048x256
  unsigned short* VupT = (unsigned short*)(ws + 54525952);   // [1024][4096] d-major
  unsigned short* ctx = (unsigned short*)(ws + 62914560);    // 4096x1024

  k_cvt_all<<<6144, 256, 0, stream>>>(x, Wqd, Wkd, Wvd, Wvu, Wo, xb, Wdb, Wvub, Wob);
  k_mabs<<<dim3(4, 4, 16), 256, 0, stream>>>(Wqu, Wku, MabsT);
  // latents: [4096,768] = xb @ Wdb^T
  k_gemm<<<dim3(32, 6, 1), 256, 0, stream>>>(xb, 1024, Wdb, 1024, 0, Lat, nullptr,
                                             4096, 768, 1024, 768, 0);
  // Qabs per head: [4096,256] = Q_lat @ MabsT[h]^T  (mode 2 = per-head scatter)
  k_gemm<<<dim3(32, 2, 16), 256, 0, stream>>>(Lat, 768, MabsT, 256, 65536, Qabs, nullptr,
                                              4096, 256, 256, 0, 2);
  // VupT [1024 d][4096 s_glob] = Wvub @ V_lat^T  (mode 0, coalesced stores)
  k_gemm<<<dim3(8, 32, 1), 256, 0, stream>>>(Wvub, 256, Lat + 512, 768, 0, VupT, nullptr,
                                             1024, 4096, 256, 4096, 0);
  k_attn<<<dim3(32, 32), 256, 0, stream>>>(Qabs, Lat, VupT, ctx);
  // out = ctx @ Wo^T + bo (fp32)
  k_gemm<<<dim3(32, 8, 1), 256, 0, stream>>>(ctx, 1024, Wob, 1024, 0, out, bo,
                                             4096, 1024, 1024, 1024, 1);
}

// Round 15
// 258.122 us; speedup vs baseline: 1.7936x; 1.7936x over previous
//
#include <hip/hip_runtime.h>

using f32x4 = __attribute__((ext_vector_type(4))) float;
using s16x8 = __attribute__((ext_vector_type(8))) short;
using u16x4 = __attribute__((ext_vector_type(4))) unsigned short;
using u32 = unsigned int;

static __device__ __forceinline__ unsigned short f2bf(float f) {
  u32 u = __builtin_bit_cast(u32, f);
  u = (u + 0x7fffu + ((u >> 16) & 1u)) >> 16;
  return (unsigned short)u;
}

static __device__ __forceinline__ void gload_lds16(const void* g, void* l) {
  __builtin_amdgcn_global_load_lds((const __attribute__((address_space(1))) void*)g,
                                   (__attribute__((address_space(3))) void*)l, 16, 0, 0);
}

// ---------------- fused fp32 -> bf16 conversion (all 6 tensors, one launch) ----------------
__global__ void k_cvt_all(const float* __restrict__ x, const float* __restrict__ Wqd,
                          const float* __restrict__ Wkd, const float* __restrict__ Wvd,
                          const float* __restrict__ Wvu, const float* __restrict__ Wo,
                          unsigned short* __restrict__ xb, unsigned short* __restrict__ Wdb,
                          unsigned short* __restrict__ Wvub, unsigned short* __restrict__ Wob) {
  int i = blockIdx.x * blockDim.x + threadIdx.x;  // float4 index, total 1572864
  const float* s;
  unsigned short* d;
  int off;
  if (i < 1048576) { s = x; d = xb; off = i; }
  else if (i < 1114112) { s = Wqd; d = Wdb; off = i - 1048576; }
  else if (i < 1179648) { s = Wkd; d = Wdb + 262144; off = i - 1114112; }
  else if (i < 1245184) { s = Wvd; d = Wdb + 524288; off = i - 1179648; }
  else if (i < 1310720) { s = Wvu; d = Wvub; off = i - 1245184; }
  else { s = Wo; d = Wob; off = i - 1310720; }
  float4 v = reinterpret_cast<const float4*>(s)[off];
  u16x4 o;
  o[0] = f2bf(v.x); o[1] = f2bf(v.y); o[2] = f2bf(v.z); o[3] = f2bf(v.w);
  reinterpret_cast<u16x4*>(d)[off] = o;
}

// ---------------- MabsT[h][k][q] = 0.125 * sum_d Wq_up[h*64+d][q] * Wk_up[h*64+d][k] ----------------
__global__ void k_mabs(const float* __restrict__ Wqu, const float* __restrict__ Wku,
                       unsigned short* __restrict__ MabsT) {
  __shared__ float sq[64][65];
  __shared__ float sk[64][65];
  int h = blockIdx.z, q0 = blockIdx.x * 64, k0 = blockIdx.y * 64;
  int t = threadIdx.x;
  for (int r = 0; r < 16; ++r) {
    int d = r * 4 + (t >> 6);
    int c = t & 63;
    sq[d][c] = Wqu[(size_t)(h * 64 + d) * 256 + q0 + c];
    sk[d][c] = Wku[(size_t)(h * 64 + d) * 256 + k0 + c];
  }
  __syncthreads();
  int kk = t >> 2, qs = t & 3;
  float acc[16];
#pragma unroll
  for (int j = 0; j < 16; ++j) acc[j] = 0.f;
  for (int d = 0; d < 64; ++d) {
    float kv = sk[d][kk];
#pragma unroll
    for (int j = 0; j < 16; ++j) acc[j] += kv * sq[d][qs + 4 * j];
  }
#pragma unroll
  for (int j = 0; j < 16; ++j)
    MabsT[((size_t)(h * 256 + k0 + kk)) * 256 + q0 + qs + 4 * j] = f2bf(acc[j] * 0.125f);
}

// ---------------- NT-GEMM, gload_lds double-buffered, templated on BN ----------------
// BM=128 fixed. 4 waves: wr=w>>1 over 64 rows, wc=w&1 over BN/2 cols.
// modes: 0 = bf16 C row-major; 1 = fp32 C row-major + bias; 2 = bf16 Qabs scatter
template <int BN>
__global__ __launch_bounds__(256) void k_gemm(
    const unsigned short* __restrict__ A, int lda,
    const unsigned short* __restrict__ B0, int ldb, long bstride,
    void* __restrict__ C, const float* __restrict__ bias,
    int M, int N, int K, int ldc, int mode) {
  constexpr int NR = BN / 32;       // fragments per wave in N
  __shared__ unsigned short As[2][128 * 32];
  __shared__ unsigned short Bs[2][BN * 32];
  int bz = blockIdx.z;
  const unsigned short* B = B0 + (size_t)bz * bstride;
  int row0 = blockIdx.x * 128, col0 = blockIdx.y * BN;
  int t = threadIdx.x;
  int lane = t & 63, w = t >> 6;
  int wr = w >> 1, wc = w & 1;
  int lc = lane & 15, kr = (lane >> 4) * 8;

#define STAGE(bufi, k0g)                                                                   \
  {                                                                                        \
    _Pragma("unroll") for (int c = 0; c < 2; ++c) {                                        \
      int f = (c * 256 + t) * 16;                                                          \
      int r = f >> 6, kb = (f & 63) >> 1;                                                  \
      gload_lds16(A + (size_t)(row0 + r) * lda + (k0g) + kb,                               \
                  (char*)&As[bufi][0] + c * 4096 + w * 1024);                              \
    }                                                                                      \
    _Pragma("unroll") for (int c = 0; c < BN / 64; ++c) {                                  \
      int f = (c * 256 + t) * 16;                                                          \
      int r = f >> 6, kb = (f & 63) >> 1;                                                  \
      gload_lds16(B + (size_t)(col0 + r) * ldb + (k0g) + kb,                               \
                  (char*)&Bs[bufi][0] + c * 4096 + w * 1024);                              \
    }                                                                                      \
  }

  f32x4 acc[4][NR];
#pragma unroll
  for (int m = 0; m < 4; ++m)
#pragma unroll
    for (int n = 0; n < NR; ++n) acc[m][n] = (f32x4){0.f, 0.f, 0.f, 0.f};

  STAGE(0, 0)
  asm volatile("s_waitcnt vmcnt(0)" ::: "memory");
  __syncthreads();

  int cur = 0;
  for (int k0 = 0; k0 < K; k0 += 32) {
    const bool pfn = (k0 + 32 < K);
    if (pfn) { STAGE(cur ^ 1, k0 + 32) }

    s16x8 af[4], bf[NR];
#pragma unroll
    for (int m = 0; m < 4; ++m)
      af[m] = *(const s16x8*)&As[cur][(wr * 64 + m * 16 + lc) * 32 + kr];
#pragma unroll
    for (int n = 0; n < NR; ++n)
      bf[n] = *(const s16x8*)&Bs[cur][(wc * (BN / 2) + n * 16 + lc) * 32 + kr];
#pragma unroll
    for (int m = 0; m < 4; ++m)
#pragma unroll
      for (int n = 0; n < NR; ++n)
        acc[m][n] = __builtin_amdgcn_mfma_f32_16x16x32_bf16(af[m], bf[n], acc[m][n], 0, 0, 0);

    asm volatile("s_waitcnt vmcnt(0)" ::: "memory");
    __syncthreads();
    cur ^= 1;
  }

  int rbase = row0 + wr * 64, cbase = col0 + wc * (BN / 2);
  int lr4 = (lane >> 4) * 4;
#pragma unroll
  for (int m = 0; m < 4; ++m)
#pragma unroll
    for (int n = 0; n < NR; ++n)
#pragma unroll
      for (int r = 0; r < 4; ++r) {
        int grow = rbase + m * 16 + lr4 + r;
        int gcol = cbase + n * 16 + lc;
        float v = acc[m][n][r];
        if (mode == 0) {
          ((unsigned short*)C)[(size_t)grow * ldc + gcol] = f2bf(v);
        } else if (mode == 1) {
          ((float*)C)[(size_t)grow * ldc + gcol] = v + bias[gcol];
        } else {
          int b_ = grow >> 11, t_ = grow & 2047;
          ((unsigned short*)C)[(((size_t)(b_ * 16 + bz)) * 2048 + t_) * 256 + gcol] = f2bf(v);
        }
      }
#undef STAGE
}

// ---------------- flash attention: R13-exact (paired tiles, 2 blocks/CU, LDS V, setprio) ----------------
__global__ __launch_bounds__(256, 2) void k_attn(
    const unsigned short* __restrict__ Qabs, const unsigned short* __restrict__ Lat,
    const unsigned short* __restrict__ VupT, unsigned short* __restrict__ ctx) {
  __shared__ unsigned short Ks[2][32 * 264];
  __shared__ unsigned short Vs[2][64 * 40];
  __shared__ unsigned short Pl[4][16 * 40];

  const int bx = blockIdx.x;
  const int bh = blockIdx.y;
  const int b = bh >> 4, h = bh & 15;
  const int t = threadIdx.x, lane = t & 63, w = t >> 6;
  const int lrow = lane & 15, hi = lane >> 4;
  const int kr = hi * 8;

  const unsigned short* Q = Qabs + (size_t)bh * 2048 * 256;
  const unsigned short* Kp = Lat + (size_t)b * 2048 * 768 + 256;
  const unsigned short* Vp = VupT + (size_t)(h * 64) * 4096 + b * 2048;
  unsigned short* Op = ctx + (size_t)b * 2048 * 1024 + h * 64;

  uint4 kstg[4];
  uint4 vstg;
  const int krr0 = t >> 5;
  const int kcc = t & 31;
  const int vrr = t >> 2, vcc = t & 3;

#define K_ISSUE(s0g)                                                           \
  {                                                                            \
    _Pragma("unroll") for (int c = 0; c < 4; ++c) kstg[c] =                    \
        *(const uint4*)(Kp + (size_t)((s0g) + c * 8 + krr0) * 768 + kcc * 8);  \
    vstg = *(const uint4*)(Vp + (size_t)vrr * 4096 + (s0g) + vcc * 8);         \
  }
#define KV_WRITE(bufi)                                                         \
  {                                                                            \
    _Pragma("unroll") for (int c = 0; c < 4; ++c)                              \
        *(uint4*)&Ks[bufi][(c * 8 + krr0) * 264 + kcc * 8] = kstg[c];          \
    *(uint4*)&Vs[bufi][vrr * 40 + vcc * 8] = vstg;                             \
  }

  for (int seg = 0; seg < 2; ++seg) {
    const int tb = (seg == 0 ? bx : 31 - bx) * 64;
    const int qb = tb + w * 16;

    s16x8 qf[8];
#pragma unroll
    for (int kk = 0; kk < 8; ++kk)
      qf[kk] = *(const s16x8*)&Q[(size_t)(qb + lrow) * 256 + kk * 32 + kr];

    f32x4 o[4];
#pragma unroll
    for (int dt = 0; dt < 4; ++dt) o[dt] = (f32x4){0.f, 0.f, 0.f, 0.f};
    float mrow[4], lsum[4];
    int myrow[4];
#pragma unroll
    for (int r = 0; r < 4; ++r) {
      mrow[r] = -1e30f;
      lsum[r] = 0.f;
      myrow[r] = qb + hi * 4 + r;
    }

    K_ISSUE(0)
    KV_WRITE(0)
    __syncthreads();

    const int nsteps = tb / 32 + 2;
    for (int st = 0; st < nsteps; ++st) {
      const int buf = st & 1;
      const int s0 = st * 32;
      const bool pfn = (st + 1 < nsteps);
      if (pfn) { K_ISSUE(s0 + 32) }

      s16x8 kfa[2][8];
#pragma unroll
      for (int hf = 0; hf < 2; ++hf)
#pragma unroll
        for (int kk = 0; kk < 8; ++kk)
          kfa[hf][kk] = *(const s16x8*)&Ks[buf][(hf * 16 + lrow) * 264 + kk * 32 + kr];

      f32x4 sf[2];
      sf[0] = (f32x4){0.f, 0.f, 0.f, 0.f};
      sf[1] = (f32x4){0.f, 0.f, 0.f, 0.f};
      __builtin_amdgcn_s_setprio(1);
#pragma unroll
      for (int kk = 0; kk < 8; ++kk) {
        sf[0] = __builtin_amdgcn_mfma_f32_16x16x32_bf16(qf[kk], kfa[0][kk], sf[0], 0, 0, 0);
        sf[1] = __builtin_amdgcn_mfma_f32_16x16x32_bf16(qf[kk], kfa[1][kk], sf[1], 0, 0, 0);
      }
      __builtin_amdgcn_s_setprio(0);

#pragma unroll
      for (int r = 0; r < 4; ++r) {
        int q = myrow[r];
        if (s0 + lrow > q) sf[0][r] = -1e30f;
        if (s0 + 16 + lrow > q) sf[1][r] = -1e30f;
        float mloc = fmaxf(sf[0][r], sf[1][r]);
        if (!__all(mloc <= mrow[r] + 8.f)) {
          float mx = mloc;
#pragma unroll
          for (int off = 1; off < 16; off <<= 1) mx = fmaxf(mx, __shfl_xor(mx, off));
          float mnew = fmaxf(mrow[r], mx);
          float scale = __expf(mrow[r] - mnew);
          mrow[r] = mnew;
          lsum[r] *= scale;
#pragma unroll
          for (int dt = 0; dt < 4; ++dt) o[dt][r] *= scale;
        }
        float p0 = __expf(sf[0][r] - mrow[r]);
        float p1 = __expf(sf[1][r] - mrow[r]);
        sf[0][r] = p0;
        sf[1][r] = p1;
        lsum[r] += p0 + p1;
      }
#pragma unroll
      for (int r = 0; r < 4; ++r) {
        Pl[w][(hi * 4 + r) * 40 + lrow] = f2bf(sf[0][r]);
        Pl[w][(hi * 4 + r) * 40 + 16 + lrow] = f2bf(sf[1][r]);
      }
      asm volatile("s_waitcnt lgkmcnt(0)" ::: "memory");
      __builtin_amdgcn_sched_barrier(0);

      s16x8 pf = *(const s16x8*)&Pl[w][lrow * 40 + kr];
      s16x8 vfa[4];
#pragma unroll
      for (int dt = 0; dt < 4; ++dt)
        vfa[dt] = *(const s16x8*)&Vs[buf][(dt * 16 + lrow) * 40 + kr];
      __builtin_amdgcn_s_setprio(1);
#pragma unroll
      for (int dt = 0; dt < 4; ++dt)
        o[dt] = __builtin_amdgcn_mfma_f32_16x16x32_bf16(pf, vfa[dt], o[dt], 0, 0, 0);
      __builtin_amdgcn_s_setprio(0);

      if (pfn) { KV_WRITE(buf ^ 1) }
      __syncthreads();
    }

#pragma unroll
    for (int r = 0; r < 4; ++r) {
      float ls = lsum[r];
#pragma unroll
      for (int off = 1; off < 16; off <<= 1) ls += __shfl_xor(ls, off);
      lsum[r] = ls;
    }
#pragma unroll
    for (int dt = 0; dt < 4; ++dt)
#pragma unroll
      for (int r = 0; r < 4; ++r) {
        float v = o[dt][r] / lsum[r];
        Op[(size_t)myrow[r] * 1024 + dt * 16 + lrow] = f2bf(v);
      }
    __syncthreads();
  }
#undef K_ISSUE
#undef KV_WRITE
}

extern "C" void kernel_launch(void* const* d_in, const int* in_sizes, int n_in,
                              void* d_out, int out_size, void* d_ws, size_t ws_size,
                              hipStream_t stream) {
  const float* x = (const float*)d_in[0];
  const float* Wqd = (const float*)d_in[2];
  const float* Wkd = (const float*)d_in[3];
  const float* Wvd = (const float*)d_in[4];
  const float* Wqu = (const float*)d_in[5];
  const float* Wku = (const float*)d_in[6];
  const float* Wvu = (const float*)d_in[7];
  const float* Wo = (const float*)d_in[8];
  const float* bo = (const float*)d_in[9];
  float* out = (float*)d_out;

  char* ws = (char*)d_ws;
  unsigned short* xb = (unsigned short*)(ws);                // 4096x1024 bf16
  unsigned short* Wdb = (unsigned short*)(ws + 8388608);     // 768x1024
  unsigned short* Wvub = (unsigned short*)(ws + 9961472);    // 1024x256
  unsigned short* Wob = (unsigned short*)(ws + 10485760);    // 1024x1024
  unsigned short* MabsT = (unsigned short*)(ws + 12582912);  // 16x256x256
  unsigned short* Lat = (unsigned short*)(ws + 14680064);    // 4096x768 (Q|K|V latents)
  unsigned short* Qabs = (unsigned short*)(ws + 20971520);   // 32x2048x256
  unsigned short* VupT = (unsigned short*)(ws + 54525952);   // [1024][4096] d-major
  unsigned short* ctx = (unsigned short*)(ws + 62914560);    // 4096x1024

  k_cvt_all<<<6144, 256, 0, stream>>>(x, Wqd, Wkd, Wvd, Wvu, Wo, xb, Wdb, Wvub, Wob);
  k_mabs<<<dim3(4, 4, 16), 256, 0, stream>>>(Wqu, Wku, MabsT);
  // latents: [4096,768] = xb @ Wdb^T   (BN=64 -> 384 blocks)
  k_gemm<64><<<dim3(32, 12, 1), 256, 0, stream>>>(xb, 1024, Wdb, 1024, 0, Lat, nullptr,
                                                  4096, 768, 1024, 768, 0);
  // Qabs per head (mode 2 scatter): BN=128, 1024 blocks (already 4/CU)
  k_gemm<128><<<dim3(32, 2, 16), 256, 0, stream>>>(Lat, 768, MabsT, 256, 65536, Qabs, nullptr,
                                                   4096, 256, 256, 0, 2);
  // VupT [1024][4096] = Wvub @ V_lat^T  (BN=64 -> 512 blocks)
  k_gemm<64><<<dim3(8, 64, 1), 256, 0, stream>>>(Wvub, 256, Lat + 512, 768, 0, VupT, nullptr,
                                                 1024, 4096, 256, 4096, 0);
  k_attn<<<dim3(16, 32), 256, 0, stream>>>(Qabs, Lat, VupT, ctx);
  // out = ctx @ Wo^T + bo (fp32, BN=64 -> 512 blocks)
  k_gemm<64><<<dim3(32, 16, 1), 256, 0, stream>>>(ctx, 1024, Wob, 1024, 0, out, bo,
                                                  4096, 1024, 1024, 1024, 1);
}